// Round 15
// baseline (67.715 us; speedup 1.0000x reference)
//
#include <hip/hip_runtime.h>
#include <hip/hip_fp8.h>

#define N_SPK 1024
#define M_UTT 16
#define D_DIM 512

typedef __attribute__((ext_vector_type(4))) int i32x4;
typedef __attribute__((ext_vector_type(8))) int i32x8;
typedef __attribute__((ext_vector_type(16))) float f32x16;

__device__ __forceinline__ float wave_sum64(float v) {
  #pragma unroll
  for (int off = 32; off >= 1; off >>= 1) v += __shfl_xor(v, off, 64);
  return v;
}

__device__ __forceinline__ unsigned int pack4_e4m3(float a, float b, float c,
                                                   float d) {
  union { __hip_fp8_e4m3 q; unsigned char u; } A, B, C, D;
  A.q = __hip_fp8_e4m3(a); B.q = __hip_fp8_e4m3(b);
  C.q = __hip_fp8_e4m3(c); D.q = __hip_fp8_e4m3(d);
  return (unsigned int)A.u | ((unsigned int)B.u << 8) |
         ((unsigned int)C.u << 16) | ((unsigned int)D.u << 24);
}

__device__ __forceinline__ void gload_lds16(const void* g, void* l) {
  __builtin_amdgcn_global_load_lds(
      (const __attribute__((address_space(1))) void*)g,
      (__attribute__((address_space(3))) void*)l, 16, 0, 0);
}

// Kernel 1: per speaker n — centroid unit vec (fp8), normalized embeddings
// (fp8), exact fp32 LOO diagonal logit pos = w*(diag+eps)+b.
__global__ __launch_bounds__(256) void prep_kernel(
    const float* __restrict__ emb, const float* __restrict__ wp,
    const float* __restrict__ bp, unsigned int* __restrict__ eU,
    unsigned int* __restrict__ cU, float* __restrict__ pos_out)
{
  const int n = blockIdx.x;
  const int t = threadIdx.x;
  __shared__ float es[M_UTT * D_DIM];
  __shared__ float Sd[D_DIM];
  __shared__ float red[4];
  __shared__ float inv_s[M_UTT];

  const float* base = emb + (size_t)n * (M_UTT * D_DIM);
  #pragma unroll
  for (int i = 0; i < 8; ++i) {
    int s = t + i * 256;
    reinterpret_cast<float4*>(es)[s] = reinterpret_cast<const float4*>(base)[s];
  }
  __syncthreads();

  #pragma unroll
  for (int rep = 0; rep < 2; ++rep) {
    int d = t + rep * 256;
    float s = 0.f;
    #pragma unroll
    for (int m = 0; m < M_UTT; ++m) s += es[m * D_DIM + d];
    Sd[d] = s;
  }
  __syncthreads();

  float p = 0.f;
  #pragma unroll
  for (int rep = 0; rep < 2; ++rep) {
    int d = t + rep * 256;
    float c = Sd[d] * (1.f / M_UTT);
    p += c * c;
  }
  p = wave_sum64(p);
  if ((t & 63) == 0) red[t >> 6] = p;
  __syncthreads();
  float cn2 = red[0] + red[1] + red[2] + red[3];
  float invc = 1.f / fmaxf(sqrtf(cn2), 1e-8f);

  // centroid unit vector -> fp8 (threads 0..127 write 4 elems each)
  if (t < 128) {
    int k0 = t * 4;
    float sc = (1.f / M_UTT) * invc;
    cU[n * 128 + t] = pack4_e4m3(Sd[k0] * sc, Sd[k0 + 1] * sc,
                                 Sd[k0 + 2] * sc, Sd[k0 + 3] * sc);
  }

  const int wid = t >> 6, lane = t & 63;
  const float w = *wp, b = *bp;
  for (int m = wid; m < M_UTT; m += 4) {
    float dot = 0.f, ne = 0.f, nl = 0.f;
    #pragma unroll
    for (int r = 0; r < 8; ++r) {
      int d = lane + r * 64;
      float e = es[m * D_DIM + d];
      float l = Sd[d] - e;
      dot += e * l; ne += e * e; nl += l * l;
    }
    dot = wave_sum64(dot); ne = wave_sum64(ne); nl = wave_sum64(nl);
    if (lane == 0) {
      float inv_e = 1.f / fmaxf(sqrtf(ne), 1e-8f);
      float inv_l = 1.f / fmaxf(sqrtf(nl) * (1.f / (M_UTT - 1)), 1e-8f);
      float diag = dot * (1.f / (M_UTT - 1)) * inv_e * inv_l;
      pos_out[n * M_UTT + m] = w * (diag + 1e-6f) + b;
      inv_s[m] = inv_e;
    }
  }
  __syncthreads();

  // normalized embeddings -> fp8 (8 iters x 4 elems per thread)
  #pragma unroll
  for (int i = 0; i < 8; ++i) {
    int wi = t + i * 256;              // word index 0..2047
    int m = wi >> 7;
    int k0 = (wi & 127) * 4;
    float sc = inv_s[m];
    eU[(size_t)n * 2048 + wi] =
        pack4_e4m3(es[m * D_DIM + k0] * sc, es[m * D_DIM + k0 + 1] * sc,
                   es[m * D_DIM + k0 + 2] * sc, es[m * D_DIM + k0 + 3] * sc);
  }
}

// ---------------- 256x256 MX-fp8 MFMA GEMM (32x32x64, unit scales) ---------
// BM=BN=256, BK=64 (64B/row-tile), 8 waves (wm=wv>>2, wn=wv&3), per-wave
// 128x64 via 4x2 frags of 32x32. LDS: A dbuf 2x16KB, B dbuf 2x16KB. Rows
// packed 2-per-128B-line; 16B segs XOR-swizzled: slot sp = seg ^ (line&7),
// seg = 2*(k>>5... ) enc: seg = (kseg) + 4*(row&1), kseg = byte k/16.
// Depth-1 prefetch, 1 barrier + 1 vmcnt(0) per tile (r13-proven loop shape).
#define NKT 8   // 512 / 64

__global__ __launch_bounds__(512, 2) void mfma_kernel(
    const char* __restrict__ eU, const char* __restrict__ cU,
    const float* __restrict__ pos, const float* __restrict__ wp,
    const float* __restrict__ bp, float* __restrict__ partial)
{
  __shared__ char ldsA[32768];
  __shared__ char ldsB[32768];
  __shared__ float pos_l[256];
  __shared__ float rowsum[4][256];

  const int t = threadIdx.x;
  const int lane = t & 63;
  const int wv = t >> 6;               // 0..7
  const int wm = wv >> 2, wn = wv & 3;

  const int bid = blockIdx.x;
  const int sw = (bid & 7) * 32 + (bid >> 3);   // XCD swizzle (256 % 8 == 0)
  const int cb = sw & 3, rb = sw >> 2;
  const int row0 = rb * 256, col0 = cb * 256;

  const float w = *wp, b = *bp;        // uniform -> s_load (lgkm, not vmcnt)
  const float bb = w * 1e-6f + b;      // fold +SIM_EPS

  // staging source offsets (2 rounds of 8KB each for A and B).
  // slot s = t + r*512: line = s>>3, sp = s&7, seg = sp ^ (line&7),
  // row = 2*line + (seg>>2), kseg = seg&3.
  unsigned int gA[2], gB[2];
  #pragma unroll
  for (int r = 0; r < 2; ++r) {
    int s = t + r * 512;
    int line = s >> 3, sp = s & 7;
    int seg = sp ^ (line & 7);
    int row = 2 * line + (seg >> 2);
    int kseg = seg & 3;
    gA[r] = (unsigned int)(row0 + row) * 512u + kseg * 16;
    gB[r] = (unsigned int)(col0 + row) * 512u + kseg * 16;
  }
  char* lA = ldsA + wv * 1024;         // gload dest: wave base + lane*16
  char* lB = ldsB + wv * 1024;

  // fragment read byte-offsets: rl = lane&31 (row-in-frag), kh = lane>>5
  const int rl = lane & 31, kh = lane >> 5;
  const int seg0 = 2 * kh + 4 * (rl & 1);
  int afb[4][2], bfb[2][2];
  #pragma unroll
  for (int mi = 0; mi < 4; ++mi) {
    int line = wm * 64 + mi * 16 + (rl >> 1);
    afb[mi][0] = line * 128 + ((seg0 ^ (line & 7)) * 16);
    afb[mi][1] = line * 128 + (((seg0 + 1) ^ (line & 7)) * 16);
  }
  #pragma unroll
  for (int nj = 0; nj < 2; ++nj) {
    int line = wn * 32 + nj * 16 + (rl >> 1);
    bfb[nj][0] = line * 128 + ((seg0 ^ (line & 7)) * 16);
    bfb[nj][1] = line * 128 + (((seg0 + 1) ^ (line & 7)) * 16);
  }

  f32x16 acc[4][2] = {};
  const int SC = 0x7F7F7F7F;           // unit e8m0 scales

  // prologue stage tile 0 (4 gloads; no prior per-lane VMEM -> exact count)
  {
    gload_lds16(eU + gA[0], lA);
    gload_lds16(eU + gA[1], lA + 8192);
    gload_lds16(cU + gB[0], lB);
    gload_lds16(cU + gB[1], lB + 8192);
  }

  for (int j = 0; j < NKT; ++j) {
    asm volatile("s_waitcnt vmcnt(0)" ::: "memory");   // tile j landed
    __builtin_amdgcn_s_barrier();      // compute(j-1) done before stage(j+1)
    if (j < NKT - 1) {
      const int bo2 = ((j + 1) & 1) << 14;
      const int d0 = (j + 1) * 64;
      gload_lds16(eU + gA[0] + d0, lA + bo2);
      gload_lds16(eU + gA[1] + d0, lA + bo2 + 8192);
      gload_lds16(cU + gB[0] + d0, lB + bo2);
      gload_lds16(cU + gB[1] + d0, lB + bo2 + 8192);
    }

    const int bo = (j & 1) << 14;
    i32x8 af[4], bf[2];
    #pragma unroll
    for (int nj = 0; nj < 2; ++nj) {
      i32x4 lo = *reinterpret_cast<const i32x4*>(ldsB + bo + bfb[nj][0]);
      i32x4 hi = *reinterpret_cast<const i32x4*>(ldsB + bo + bfb[nj][1]);
      bf[nj] = __builtin_shufflevector(lo, hi, 0, 1, 2, 3, 4, 5, 6, 7);
    }
    #pragma unroll
    for (int mi = 0; mi < 4; ++mi) {
      i32x4 lo = *reinterpret_cast<const i32x4*>(ldsA + bo + afb[mi][0]);
      i32x4 hi = *reinterpret_cast<const i32x4*>(ldsA + bo + afb[mi][1]);
      af[mi] = __builtin_shufflevector(lo, hi, 0, 1, 2, 3, 4, 5, 6, 7);
    }
    __builtin_amdgcn_s_setprio(1);
    #pragma unroll
    for (int mi = 0; mi < 4; ++mi)
      #pragma unroll
      for (int nj = 0; nj < 2; ++nj)
        acc[mi][nj] = __builtin_amdgcn_mfma_scale_f32_32x32x64_f8f6f4(
            af[mi], bf[nj], acc[mi][nj], 0, 0, 0, SC, 0, SC);
    __builtin_amdgcn_s_setprio(0);
  }

  // ---- fused epilogue: exp/diag, per-row partial sums over this cb ----
  if (t < 256) pos_l[t] = pos[row0 + t];
  __syncthreads();

  // C/D 32x32 layout: col = col0 + wn*64 + nj*32 + rl;
  // row = wm*128 + mi*32 + (reg&3) + 8*(reg>>2) + 4*kh
  #pragma unroll
  for (int mi = 0; mi < 4; ++mi) {
    #pragma unroll
    for (int reg = 0; reg < 16; ++reg) {
      const int row_loc = wm * 128 + mi * 32 + (reg & 3) + 8 * (reg >> 2) + 4 * kh;
      const int diag_col = (row0 + row_loc) >> 4;
      float s = 0.f;
      #pragma unroll
      for (int nj = 0; nj < 2; ++nj) {
        const int col = col0 + wn * 64 + nj * 32 + rl;
        float arg = w * acc[mi][nj][reg] + bb;
        if (col == diag_col) arg = pos_l[row_loc];
        s += __expf(arg);
      }
      s += __shfl_xor(s, 1, 64);
      s += __shfl_xor(s, 2, 64);
      s += __shfl_xor(s, 4, 64);
      s += __shfl_xor(s, 8, 64);
      s += __shfl_xor(s, 16, 64);
      if (rl == 0) rowsum[wn][row_loc] = s;
    }
  }
  __syncthreads();
  if (t < 256)
    partial[(size_t)cb * (N_SPK * M_UTT) + row0 + t] =
        rowsum[0][t] + rowsum[1][t] + rowsum[2][t] + rowsum[3][t];
}

// Kernel 3: fused log-sum + global reduce, single block (deterministic).
__global__ __launch_bounds__(1024) void finalize_kernel(
    const float* __restrict__ partial, const float* __restrict__ pos,
    float* __restrict__ out)
{
  const int t = threadIdx.x;
  float v = 0.f;
  #pragma unroll
  for (int i = 0; i < 16; ++i) {
    const int r = t + i * 1024;
    float s = partial[r] + partial[16384 + r] + partial[32768 + r] +
              partial[49152 + r];
    v += logf(s + 1e-6f) - pos[r];
  }
  v = wave_sum64(v);
  __shared__ float red[16];
  if ((t & 63) == 0) red[t >> 6] = v;
  __syncthreads();
  if (t == 0) {
    float s = 0.f;
    #pragma unroll
    for (int i = 0; i < 16; ++i) s += red[i];
    out[0] = s;
  }
}

extern "C" void kernel_launch(void* const* d_in, const int* in_sizes, int n_in,
                              void* d_out, int out_size, void* d_ws, size_t ws_size,
                              hipStream_t stream) {
  const float* emb = (const float*)d_in[0];
  const float* wp  = (const float*)d_in[1];
  const float* bp  = (const float*)d_in[2];
  float* out = (float*)d_out;

  char* wsb = (char*)d_ws;
  unsigned int* eU  = (unsigned int*)wsb;                       // 8,388,608 B
  unsigned int* cU  = (unsigned int*)(wsb + 8388608);           //   524,288 B
  float* pos        = (float*)(wsb + 8388608 + 524288);         //    65,536 B
  float* partial    = (float*)(wsb + 8388608 + 524288 + 65536); //   262,144 B

  prep_kernel<<<N_SPK, 256, 0, stream>>>(emb, wp, bp, eU, cU, pos);
  mfma_kernel<<<256, 512, 0, stream>>>(
      (const char*)eU, (const char*)cU, pos, wp, bp, partial);
  finalize_kernel<<<1, 1024, 0, stream>>>(partial, pos, out);
}

// Round 16
// 67.477 us; speedup vs baseline: 1.0035x; 1.0035x over previous
//
#include <hip/hip_runtime.h>
#include <hip/hip_fp8.h>

#define N_SPK 1024
#define M_UTT 16
#define D_DIM 512

typedef __attribute__((ext_vector_type(4))) int i32x4;
typedef __attribute__((ext_vector_type(8))) int i32x8;
typedef __attribute__((ext_vector_type(16))) float f32x16;

__device__ __forceinline__ float wave_sum64(float v) {
  #pragma unroll
  for (int off = 32; off >= 1; off >>= 1) v += __shfl_xor(v, off, 64);
  return v;
}

__device__ __forceinline__ unsigned int pack4_e4m3(float a, float b, float c,
                                                   float d) {
  union { __hip_fp8_e4m3 q; unsigned char u; } A, B, C, D;
  A.q = __hip_fp8_e4m3(a); B.q = __hip_fp8_e4m3(b);
  C.q = __hip_fp8_e4m3(c); D.q = __hip_fp8_e4m3(d);
  return (unsigned int)A.u | ((unsigned int)B.u << 8) |
         ((unsigned int)C.u << 16) | ((unsigned int)D.u << 24);
}

__device__ __forceinline__ void gload_lds16(const void* g, void* l) {
  __builtin_amdgcn_global_load_lds(
      (const __attribute__((address_space(1))) void*)g,
      (__attribute__((address_space(3))) void*)l, 16, 0, 0);
}

// Blocked fp8 layouts (16B granules, LDS-image order so GEMM staging is
// contiguous):
//  eU: word idx = (k>>6)*262144 + (row>>8)*4096 + ((k>>4)&3)*1024
//               + (row&255)*4 + ((k&15)>>2)          [8 MB total]
//  cU: word idx = (k>>6)*16384  + (col>>8)*4096 + ((k>>4)&3)*1024
//               + (col&255)*4 + ((k&15)>>2)          [512 KB total]

// Kernel 1: per speaker n — centroid unit vec (fp8, blocked), normalized
// embeddings (fp8, blocked), exact fp32 LOO diagonal logit pos.
__global__ __launch_bounds__(256) void prep_kernel(
    const float* __restrict__ emb, const float* __restrict__ wp,
    const float* __restrict__ bp, unsigned int* __restrict__ eU,
    unsigned int* __restrict__ cU, float* __restrict__ pos_out)
{
  const int n = blockIdx.x;
  const int t = threadIdx.x;
  __shared__ float es[M_UTT * D_DIM];
  __shared__ float Sd[D_DIM];
  __shared__ float red[4];
  __shared__ float inv_s[M_UTT];

  const float* base = emb + (size_t)n * (M_UTT * D_DIM);
  #pragma unroll
  for (int i = 0; i < 8; ++i) {
    int s = t + i * 256;
    reinterpret_cast<float4*>(es)[s] = reinterpret_cast<const float4*>(base)[s];
  }
  __syncthreads();

  #pragma unroll
  for (int rep = 0; rep < 2; ++rep) {
    int d = t + rep * 256;
    float s = 0.f;
    #pragma unroll
    for (int m = 0; m < M_UTT; ++m) s += es[m * D_DIM + d];
    Sd[d] = s;
  }
  __syncthreads();

  float p = 0.f;
  #pragma unroll
  for (int rep = 0; rep < 2; ++rep) {
    int d = t + rep * 256;
    float c = Sd[d] * (1.f / M_UTT);
    p += c * c;
  }
  p = wave_sum64(p);
  if ((t & 63) == 0) red[t >> 6] = p;
  __syncthreads();
  float cn2 = red[0] + red[1] + red[2] + red[3];
  float invc = 1.f / fmaxf(sqrtf(cn2), 1e-8f);

  // centroid unit vector -> fp8, blocked layout (threads 0..127, 4 elems each)
  if (t < 128) {
    int k0 = t * 4;
    float sc = (1.f / M_UTT) * invc;
    unsigned int idx = (unsigned int)(k0 >> 6) * 16384u + (n >> 8) * 4096u +
                       ((k0 >> 4) & 3) * 1024u + (n & 255) * 4u +
                       ((k0 & 15) >> 2);
    cU[idx] = pack4_e4m3(Sd[k0] * sc, Sd[k0 + 1] * sc,
                         Sd[k0 + 2] * sc, Sd[k0 + 3] * sc);
  }

  const int wid = t >> 6, lane = t & 63;
  const float w = *wp, b = *bp;
  for (int m = wid; m < M_UTT; m += 4) {
    float dot = 0.f, ne = 0.f, nl = 0.f;
    #pragma unroll
    for (int r = 0; r < 8; ++r) {
      int d = lane + r * 64;
      float e = es[m * D_DIM + d];
      float l = Sd[d] - e;
      dot += e * l; ne += e * e; nl += l * l;
    }
    dot = wave_sum64(dot); ne = wave_sum64(ne); nl = wave_sum64(nl);
    if (lane == 0) {
      float inv_e = 1.f / fmaxf(sqrtf(ne), 1e-8f);
      float inv_l = 1.f / fmaxf(sqrtf(nl) * (1.f / (M_UTT - 1)), 1e-8f);
      float diag = dot * (1.f / (M_UTT - 1)) * inv_e * inv_l;
      pos_out[n * M_UTT + m] = w * (diag + 1e-6f) + b;
      inv_s[m] = inv_e;
    }
  }
  __syncthreads();

  // normalized embeddings -> fp8, blocked layout (8 iters x 4 elems)
  #pragma unroll
  for (int i = 0; i < 8; ++i) {
    int wi = t + i * 256;              // word index 0..2047
    int m = wi >> 7;
    int k0 = (wi & 127) * 4;
    float sc = inv_s[m];
    int row = n * M_UTT + m;
    unsigned int idx = (unsigned int)(k0 >> 6) * 262144u + (row >> 8) * 4096u +
                       ((k0 >> 4) & 3) * 1024u + (row & 255) * 4u +
                       ((k0 & 15) >> 2);
    eU[idx] =
        pack4_e4m3(es[m * D_DIM + k0] * sc, es[m * D_DIM + k0 + 1] * sc,
                   es[m * D_DIM + k0 + 2] * sc, es[m * D_DIM + k0 + 3] * sc);
  }
}

// ---------------- 256x256 MX-fp8 MFMA GEMM (32x32x64, unit scales) ---------
// BM=BN=256, BK=64, 8 waves (wm=wv>>2, wn=wv&3), per-wave 128x64 via 4x2
// frags of 32x32. Blocked global layout -> staging is 4 fully-coalesced
// contiguous 8KB gload_lds rounds per tile; LDS image = [kseg][256 rows]x16B.
// Frag semantics identical to r15 (hardware-verified pass): A/B row=lane&31,
// k-half=lane>>5 (ksegs 2kh,2kh+1); C/D 32x32 mapping per m74/m101.
// Depth-1 prefetch, 1 barrier + 1 vmcnt(0) per tile (r13-proven loop shape).
#define NKT 8   // 512 / 64

__global__ __launch_bounds__(512, 2) void mfma_kernel(
    const char* __restrict__ eU, const char* __restrict__ cU,
    const float* __restrict__ pos, const float* __restrict__ wp,
    const float* __restrict__ bp, float* __restrict__ partial)
{
  __shared__ char ldsA[32768];
  __shared__ char ldsB[32768];
  __shared__ float pos_l[256];
  __shared__ float rowsum[4][256];

  const int t = threadIdx.x;
  const int lane = t & 63;
  const int wv = t >> 6;               // 0..7
  const int wm = wv >> 2, wn = wv & 3;

  const int bid = blockIdx.x;
  const int sw = (bid & 7) * 32 + (bid >> 3);   // XCD swizzle (256 % 8 == 0)
  const int cb = sw & 3, rb = sw >> 2;
  const int row0 = rb * 256, col0 = cb * 256;

  const float w = *wp, b = *bp;        // uniform -> s_load (lgkm, not vmcnt)
  const float bb = w * 1e-6f + b;      // fold +SIM_EPS

  // staging: contiguous per tile; per-lane src = base + t*16
  const char* gA0 = eU + (size_t)rb * 16384 + t * 16;
  const char* gB0 = cU + (size_t)cb * 16384 + t * 16;
  char* lA = ldsA + wv * 1024;
  char* lB = ldsB + wv * 1024;

  // fragment read byte-offsets: row-in-frag rl = lane&31, k-half kh = lane>>5
  const int rl = lane & 31, kh = lane >> 5;
  int afb[4], bfb[2];
  #pragma unroll
  for (int mi = 0; mi < 4; ++mi)
    afb[mi] = (2 * kh) * 4096 + (wm * 128 + mi * 32 + rl) * 16;
  #pragma unroll
  for (int nj = 0; nj < 2; ++nj)
    bfb[nj] = (2 * kh) * 4096 + (wn * 64 + nj * 32 + rl) * 16;

  f32x16 acc[4][2] = {};
  const int SC = 0x7F7F7F7F;           // unit e8m0 scales

  // prologue: stage tile 0 (4 gloads; no prior per-lane VMEM -> exact count)
  gload_lds16(gA0,        lA);
  gload_lds16(gA0 + 8192, lA + 8192);
  gload_lds16(gB0,        lB);
  gload_lds16(gB0 + 8192, lB + 8192);

  for (int j = 0; j < NKT; ++j) {
    asm volatile("s_waitcnt vmcnt(0)" ::: "memory");   // tile j landed
    __builtin_amdgcn_s_barrier();      // compute(j-1) done before stage(j+1)
    if (j < NKT - 1) {
      const int bo2 = ((j + 1) & 1) << 14;
      const char* ga = gA0 + (size_t)(j + 1) * 1048576;
      const char* gb = gB0 + (size_t)(j + 1) * 65536;
      gload_lds16(ga,        lA + bo2);
      gload_lds16(ga + 8192, lA + bo2 + 8192);
      gload_lds16(gb,        lB + bo2);
      gload_lds16(gb + 8192, lB + bo2 + 8192);
    }

    const int bo = (j & 1) << 14;
    i32x8 af[4], bf[2];
    #pragma unroll
    for (int nj = 0; nj < 2; ++nj) {
      i32x4 lo = *reinterpret_cast<const i32x4*>(ldsB + bo + bfb[nj]);
      i32x4 hi = *reinterpret_cast<const i32x4*>(ldsB + bo + bfb[nj] + 4096);
      bf[nj] = __builtin_shufflevector(lo, hi, 0, 1, 2, 3, 4, 5, 6, 7);
    }
    #pragma unroll
    for (int mi = 0; mi < 4; ++mi) {
      i32x4 lo = *reinterpret_cast<const i32x4*>(ldsA + bo + afb[mi]);
      i32x4 hi = *reinterpret_cast<const i32x4*>(ldsA + bo + afb[mi] + 4096);
      af[mi] = __builtin_shufflevector(lo, hi, 0, 1, 2, 3, 4, 5, 6, 7);
    }
    __builtin_amdgcn_s_setprio(1);
    #pragma unroll
    for (int mi = 0; mi < 4; ++mi)
      #pragma unroll
      for (int nj = 0; nj < 2; ++nj)
        acc[mi][nj] = __builtin_amdgcn_mfma_scale_f32_32x32x64_f8f6f4(
            af[mi], bf[nj], acc[mi][nj], 0, 0, 0, SC, 0, SC);
    __builtin_amdgcn_s_setprio(0);
  }

  // ---- fused epilogue: exp/diag, per-row partial sums over this cb ----
  if (t < 256) pos_l[t] = pos[row0 + t];
  __syncthreads();

  // C/D 32x32 layout: col = col0 + wn*64 + nj*32 + rl;
  // row = wm*128 + mi*32 + (reg&3) + 8*(reg>>2) + 4*kh   (r15-verified)
  #pragma unroll
  for (int mi = 0; mi < 4; ++mi) {
    #pragma unroll
    for (int reg = 0; reg < 16; ++reg) {
      const int row_loc = wm * 128 + mi * 32 + (reg & 3) + 8 * (reg >> 2) + 4 * kh;
      const int diag_col = (row0 + row_loc) >> 4;
      float s = 0.f;
      #pragma unroll
      for (int nj = 0; nj < 2; ++nj) {
        const int col = col0 + wn * 64 + nj * 32 + rl;
        float arg = w * acc[mi][nj][reg] + bb;
        if (col == diag_col) arg = pos_l[row_loc];
        s += __expf(arg);
      }
      s += __shfl_xor(s, 1, 64);
      s += __shfl_xor(s, 2, 64);
      s += __shfl_xor(s, 4, 64);
      s += __shfl_xor(s, 8, 64);
      s += __shfl_xor(s, 16, 64);
      if (rl == 0) rowsum[wn][row_loc] = s;
    }
  }
  __syncthreads();
  if (t < 256)
    partial[(size_t)cb * (N_SPK * M_UTT) + row0 + t] =
        rowsum[0][t] + rowsum[1][t] + rowsum[2][t] + rowsum[3][t];
}

// Kernel 3: fused log-sum + global reduce, single block (deterministic).
__global__ __launch_bounds__(1024) void finalize_kernel(
    const float* __restrict__ partial, const float* __restrict__ pos,
    float* __restrict__ out)
{
  const int t = threadIdx.x;
  float v = 0.f;
  #pragma unroll
  for (int i = 0; i < 16; ++i) {
    const int r = t + i * 1024;
    float s = partial[r] + partial[16384 + r] + partial[32768 + r] +
              partial[49152 + r];
    v += logf(s + 1e-6f) - pos[r];
  }
  v = wave_sum64(v);
  __shared__ float red[16];
  if ((t & 63) == 0) red[t >> 6] = v;
  __syncthreads();
  if (t == 0) {
    float s = 0.f;
    #pragma unroll
    for (int i = 0; i < 16; ++i) s += red[i];
    out[0] = s;
  }
}

extern "C" void kernel_launch(void* const* d_in, const int* in_sizes, int n_in,
                              void* d_out, int out_size, void* d_ws, size_t ws_size,
                              hipStream_t stream) {
  const float* emb = (const float*)d_in[0];
  const float* wp  = (const float*)d_in[1];
  const float* bp  = (const float*)d_in[2];
  float* out = (float*)d_out;

  char* wsb = (char*)d_ws;
  unsigned int* eU  = (unsigned int*)wsb;                       // 8,388,608 B
  unsigned int* cU  = (unsigned int*)(wsb + 8388608);           //   524,288 B
  float* pos        = (float*)(wsb + 8388608 + 524288);         //    65,536 B
  float* partial    = (float*)(wsb + 8388608 + 524288 + 65536); //   262,144 B

  prep_kernel<<<N_SPK, 256, 0, stream>>>(emb, wp, bp, eU, cU, pos);
  mfma_kernel<<<256, 512, 0, stream>>>(
      (const char*)eU, (const char*)cU, pos, wp, bp, partial);
  finalize_kernel<<<1, 1024, 0, stream>>>(partial, pos, out);
}